// Round 1
// baseline (488.845 us; speedup 1.0000x reference)
//
#include <hip/hip_runtime.h>

#define NPIX 16384   // 128*128
#define NN   256     // max_nodes
#define CC   256     // NFEAT
#define HH   128     // SCORER_HIDDEN
#define EE   65280   // NN*(NN-1)
#define BB   4

// ---------------- Kernel 1: sigmoid + exact top-k via bitonic sort ----------------
// key = (float_bits(prob) << 32) | (0xFFFFFFFF - idx)
// sort descending => prob desc, ties -> lower idx first (matches jax.lax.top_k)
__global__ __launch_bounds__(1024) void k_topk(
    const float* __restrict__ jl, const float* __restrict__ off,
    int* __restrict__ topi, int* __restrict__ valid, float* __restrict__ inv_deg,
    float* __restrict__ out_nodes)
{
  __shared__ unsigned long long keys[NPIX];   // 128 KiB
  __shared__ int s_cnt;
  const int b = blockIdx.x;
  const int tid = threadIdx.x;
  if (tid == 0) s_cnt = 0;
  const float* p = jl + (size_t)b * NPIX;
  for (int i = tid; i < NPIX; i += 1024) {
    float x = p[i];
    float pr = 1.0f / (1.0f + expf(-x));
    unsigned bits = __float_as_uint(pr);            // prob in (0,1): bits monotone
    keys[i] = ((unsigned long long)bits << 32) | (unsigned)(0xFFFFFFFFu - (unsigned)i);
  }
  __syncthreads();
  for (int k = 2; k <= NPIX; k <<= 1) {
    for (int j = k >> 1; j > 0; j >>= 1) {
      for (int i = tid; i < NPIX; i += 1024) {
        int l = i ^ j;
        if (l > i) {
          unsigned long long a = keys[i], c = keys[l];
          bool desc = (i & k) == 0;
          if (desc ? (a < c) : (a > c)) { keys[i] = c; keys[l] = a; }
        }
      }
      __syncthreads();
    }
  }
  if (tid < NN) {
    unsigned long long kk = keys[tid];
    int idx = (int)(0xFFFFFFFFu - (unsigned)(kk & 0xFFFFFFFFull));
    unsigned bits = (unsigned)(kk >> 32);
    int v = bits > 0x3F000000u ? 1 : 0;             // prob > 0.5f strictly
    topi[b*NN + tid] = idx;
    valid[b*NN + tid] = v;
    if (v) atomicAdd(&s_cnt, 1);
    int iy = idx >> 7;          // w = 128
    int ix = idx & 127;
    float yo = off[((size_t)b*2 + 0) * NPIX + idx];
    float xo = off[((size_t)b*2 + 1) * NPIX + idx];
    float xs = ((float)ix + 0.5f + xo) * 4.0f;      // STRIDE = 4
    float ys = ((float)iy + 0.5f + yo) * 4.0f;
    out_nodes[(b*NN + tid)*2 + 0] = xs;
    out_nodes[(b*NN + tid)*2 + 1] = ys;
  }
  __syncthreads();
  if (tid < NN) {
    int V = s_cnt;
    int v = valid[b*NN + tid];
    // deg[j] = valid[j]*(V-1); inv_deg = deg>0 ? 1/deg : 0
    inv_deg[b*NN + tid] = (v && V >= 2) ? 1.0f / (float)(V - 1) : 0.0f;
  }
}

// ---------------- Kernel 2: gather node features, mask by valid ----------------
__global__ __launch_bounds__(256) void k_gather(
    const float* __restrict__ nmap, const int* __restrict__ topi,
    const int* __restrict__ valid, float* __restrict__ x)
{
  const int bn = blockIdx.x;          // b*256 + n
  const int b = bn >> 8;
  const int c = threadIdx.x;
  int pix = topi[bn];
  int v = valid[bn];
  float val = nmap[(((size_t)b*CC + c) << 14) + pix];
  x[(size_t)bn*CC + c] = v ? val : 0.0f;
}

// ---------------- Kernel 3: column sum S[c] = sum_n x[n][c] ----------------
__global__ __launch_bounds__(256) void k_colsum(
    const float* __restrict__ x, float* __restrict__ S)
{
  const int b = blockIdx.x, c = threadIdx.x;
  const float* xb = x + (size_t)b*NN*CC;
  float s = 0.f;
  for (int n = 0; n < NN; ++n) s += xb[n*CC + c];
  S[b*CC + c] = s;
}

// ---------------- Kernel 4: fused GNN layer ----------------
// out = relu(x @ Wself + ((S - x)*inv_deg) @ Wnbr + bias) * valid
__global__ __launch_bounds__(256) void k_gnn(
    const float* __restrict__ x, const float* __restrict__ S,
    const float* __restrict__ inv_deg, const int* __restrict__ valid,
    const float* __restrict__ Wself, const float* __restrict__ Wnbr,
    const float* __restrict__ bias, float* __restrict__ xout,
    float* __restrict__ out_emb)   // may be null
{
  __shared__ float sx[8][CC];
  __shared__ float sz[8][CC];
  const int b = blockIdx.x >> 5;
  const int n0 = (blockIdx.x & 31) * 8;
  const int tid = threadIdx.x;
  float Sc = S[b*CC + tid];
  #pragma unroll
  for (int r = 0; r < 8; ++r) {
    float a = x[((size_t)(b*NN + n0 + r))*CC + tid];
    sx[r][tid] = a;
    float inv = inv_deg[b*NN + n0 + r];
    sz[r][tid] = (Sc - a) * inv;
  }
  __syncthreads();
  float acc[8];
  #pragma unroll
  for (int r = 0; r < 8; ++r) acc[r] = 0.f;
  for (int c = 0; c < CC; ++c) {
    float w1 = Wself[c*CC + tid];
    float w2 = Wnbr[c*CC + tid];
    #pragma unroll
    for (int r = 0; r < 8; ++r)
      acc[r] += sx[r][c]*w1 + sz[r][c]*w2;
  }
  float bv = bias[tid];
  #pragma unroll
  for (int r = 0; r < 8; ++r) {
    int v = valid[b*NN + n0 + r];
    float o = fmaxf(acc[r] + bv, 0.f);
    o = v ? o : 0.f;
    size_t oi = ((size_t)(b*NN + n0 + r))*CC + tid;
    xout[oi] = o;
    if (out_emb) out_emb[oi] = o;
  }
}

// ---------------- Kernel 5: u = x@Ws1[:C], v_t = (x@Ws1[C:])^T ----------------
__global__ __launch_bounds__(128) void k_uv(
    const float* __restrict__ x, const float* __restrict__ Ws1,
    float* __restrict__ u, float* __restrict__ vt)
{
  __shared__ float sx[8][CC];
  const int b = blockIdx.x >> 5;
  const int n0 = (blockIdx.x & 31) * 8;
  const int tid = threadIdx.x;     // h
  #pragma unroll
  for (int r = 0; r < 8; ++r)
    for (int c = tid; c < CC; c += 128)
      sx[r][c] = x[((size_t)(b*NN + n0 + r))*CC + c];
  __syncthreads();
  float au[8] = {0,0,0,0,0,0,0,0};
  float av[8] = {0,0,0,0,0,0,0,0};
  for (int c = 0; c < CC; ++c) {
    float w1 = Ws1[c*HH + tid];
    float w2 = Ws1[(CC + c)*HH + tid];
    #pragma unroll
    for (int r = 0; r < 8; ++r) { au[r] += sx[r][c]*w1; av[r] += sx[r][c]*w2; }
  }
  #pragma unroll
  for (int r = 0; r < 8; ++r) {
    u [((size_t)(b*NN + n0 + r))*HH + tid] = au[r];
    vt[((size_t)b*HH + tid)*NN + (n0 + r)] = av[r];
  }
}

// ---------------- Kernel 6: per-edge scorer ----------------
__global__ __launch_bounds__(256) void k_edges(
    const float* __restrict__ u, const float* __restrict__ vt,
    const float* __restrict__ bs1, const float* __restrict__ Ws2,
    const float* __restrict__ bs2, const int* __restrict__ valid,
    float* __restrict__ out_logits, float* __restrict__ out_keep)
{
  __shared__ float su[HH], sb1[HH], sw2[HH];
  const int b = blockIdx.x >> 8;
  const int i = blockIdx.x & 255;   // src node
  const int j = threadIdx.x;        // dst node
  if (j < HH) {
    su[j]  = u[((size_t)(b*NN + i))*HH + j];
    sb1[j] = bs1[j];
    sw2[j] = Ws2[j];
  }
  __syncthreads();
  float acc = 0.f;
  const float* vrow = vt + (size_t)b*HH*NN;
  for (int h = 0; h < HH; ++h) {
    float t = su[h] + vrow[h*NN + j] + sb1[h];
    acc += fmaxf(t, 0.f) * sw2[h];
  }
  acc += bs2[0];
  if (j != i) {
    int e = i*255 + (j < i ? j : j - 1);
    int ev = valid[b*NN + i] & valid[b*NN + j];
    out_logits[(size_t)b*EE + e] = acc;
    out_keep  [(size_t)b*EE + e] = (acc > 0.f && ev) ? 1.0f : 0.0f;
  }
}

extern "C" void kernel_launch(void* const* d_in, const int* in_sizes, int n_in,
                              void* d_out, int out_size, void* d_ws, size_t ws_size,
                              hipStream_t stream) {
  const float* jl    = (const float*)d_in[0];
  const float* off   = (const float*)d_in[1];
  const float* nmap  = (const float*)d_in[2];
  const float* Wself = (const float*)d_in[3];
  const float* Wnbr  = (const float*)d_in[4];
  const float* bg    = (const float*)d_in[5];
  const float* Ws1   = (const float*)d_in[6];
  const float* bs1   = (const float*)d_in[7];
  const float* Ws2   = (const float*)d_in[8];
  const float* bs2   = (const float*)d_in[9];

  char* ws = (char*)d_ws;
  int*   topi    = (int*)  (ws + 0);                 //  4 KiB
  int*   valid   = (int*)  (ws + 4096);              //  4 KiB
  float* inv_deg = (float*)(ws + 8192);              //  4 KiB
  float* S       = (float*)(ws + 12288);             //  4 KiB
  float* xa      = (float*)(ws + 16384);             //  1 MiB
  float* xb      = (float*)(ws + 16384 + 1048576);   //  1 MiB
  float* u       = (float*)(ws + 2113536);           //  512 KiB
  float* vt      = (float*)(ws + 2637824);           //  512 KiB

  float* out        = (float*)d_out;
  float* out_nodes  = out;                  // [4,256,2]   -> 2048
  float* out_emb    = out + 2048;           // [4,256,256] -> 262144
  float* out_logits = out + 264192;         // [4,65280]   -> 261120
  float* out_keep   = out + 525312;         // [4,65280]   -> 261120

  hipLaunchKernelGGL(k_topk,   dim3(BB),     dim3(1024), 0, stream,
                     jl, off, topi, valid, inv_deg, out_nodes);
  hipLaunchKernelGGL(k_gather, dim3(BB*NN),  dim3(256),  0, stream,
                     nmap, topi, valid, xa);

  float* xc = xa; float* xn = xb;
  for (int l = 0; l < 3; ++l) {
    hipLaunchKernelGGL(k_colsum, dim3(BB),   dim3(256), 0, stream, xc, S);
    hipLaunchKernelGGL(k_gnn,    dim3(BB*32),dim3(256), 0, stream,
                       xc, S, inv_deg, valid,
                       Wself + (size_t)l*CC*CC, Wnbr + (size_t)l*CC*CC, bg + l*CC,
                       xn, (l == 2) ? out_emb : (float*)nullptr);
    float* t = xc; xc = xn; xn = t;
  }

  hipLaunchKernelGGL(k_uv,    dim3(BB*32), dim3(128), 0, stream, xc, Ws1, u, vt);
  hipLaunchKernelGGL(k_edges, dim3(BB*NN), dim3(256), 0, stream,
                     u, vt, bs1, Ws2, bs2, valid, out_logits, out_keep);
}

// Round 2
// 276.820 us; speedup vs baseline: 1.7659x; 1.7659x over previous
//
#include <hip/hip_runtime.h>

#define NPIX 16384   // 128*128
#define NN   256     // max_nodes
#define CC   256     // NFEAT
#define HH   128     // SCORER_HIDDEN
#define EE   65280   // NN*(NN-1)
#define BB   4
#define NG   8       // histogram privatization groups

// ---------------- Kernel 1: sigmoid + exact top-k via radix select ----------------
// key = (float_bits(prob) << 32) | (0xFFFFFFFF - idx)  -- unique per pixel
// top-256 keys descending => prob desc, ties -> lower idx first (matches jax.lax.top_k)
__global__ __launch_bounds__(1024) void k_topk(
    const float* __restrict__ jl, const float* __restrict__ off,
    int* __restrict__ topi, int* __restrict__ valid, float* __restrict__ inv_deg,
    float* __restrict__ out_nodes)
{
  __shared__ unsigned long long keys[NPIX];     // 128 KiB
  __shared__ unsigned long long s_sel[NN];      // 2 KiB
  __shared__ int hist[NG][256];                 // 8 KiB
  __shared__ int histT[256];                    // 1 KiB
  __shared__ unsigned long long s_T;
  __shared__ int s_digit, s_krem, s_cnt, s_vcnt, s_break;

  const int b = blockIdx.x;
  const int tid = threadIdx.x;
  const int grp = (tid >> 7) & (NG - 1);
  if (tid == 0) { s_cnt = 0; s_vcnt = 0; s_break = 0; }

  const float* p = jl + (size_t)b * NPIX;
  for (int i = tid; i < NPIX; i += 1024) {
    float x = p[i];
    float pr = 1.0f / (1.0f + expf(-x));
    unsigned bits = __float_as_uint(pr);        // prob in (0,1]: bits monotone
    keys[i] = ((unsigned long long)bits << 32) | (unsigned)(0xFFFFFFFFu - (unsigned)i);
  }

  // ---- radix select: find T = 256th largest key ----
  unsigned long long prefix = 0;
  int k = NN;
  int shift = 56;
  for (int pass = 0; pass < 8; ++pass) {
    shift = 56 - 8 * pass;
    for (int i = tid; i < NG * 256; i += 1024) ((int*)hist)[i] = 0;
    __syncthreads();   // also covers keys[] writes on pass 0 / s_digit reads on later passes
    unsigned long long pmask = (pass == 0) ? 0ULL : (~0ULL << (shift + 8));
    for (int i = tid; i < NPIX; i += 1024) {
      unsigned long long kk = keys[i];
      if ((kk & pmask) == prefix)
        atomicAdd(&hist[grp][(int)((kk >> shift) & 255)], 1);
    }
    __syncthreads();
    if (tid < 256) {
      int t = 0;
      #pragma unroll
      for (int g = 0; g < NG; ++g) t += hist[g][tid];
      histT[tid] = t;
    }
    __syncthreads();
    if (tid == 0) {
      int cum = 0, bb = 255;
      for (;; --bb) { cum += histT[bb]; if (cum >= k || bb == 0) break; }
      s_digit = bb;
      s_krem = k - (cum - histT[bb]);
      s_break = (histT[bb] == 1);
    }
    __syncthreads();
    prefix |= ((unsigned long long)s_digit) << shift;
    k = s_krem;
    if (s_break) break;
  }

  // ---- recover exact threshold key T (unique match of known-prefix bits) ----
  unsigned long long known_mask = (shift == 0) ? ~0ULL : (~0ULL << shift);
  for (int i = tid; i < NPIX; i += 1024) {
    unsigned long long kk = keys[i];
    if ((kk & known_mask) == prefix) s_T = kk;
  }
  __syncthreads();
  unsigned long long T = s_T;

  // ---- compact the exactly-256 keys >= T ----
  for (int i = tid; i < NPIX; i += 1024) {
    unsigned long long kk = keys[i];
    if (kk >= T) { int pos = atomicAdd(&s_cnt, 1); s_sel[pos] = kk; }
  }
  __syncthreads();

  // ---- bitonic sort 256 keys descending ----
  for (int kk2 = 2; kk2 <= NN; kk2 <<= 1) {
    for (int j = kk2 >> 1; j > 0; j >>= 1) {
      if (tid < NN) {
        int i = tid, l = i ^ j;
        if (l > i) {
          unsigned long long a = s_sel[i], c = s_sel[l];
          bool desc = (i & kk2) == 0;
          if (desc ? (a < c) : (a > c)) { s_sel[i] = c; s_sel[l] = a; }
        }
      }
      __syncthreads();
    }
  }

  // ---- emit topi / valid / nodes ----
  if (tid < NN) {
    unsigned long long kk = s_sel[tid];
    int idx = (int)(0xFFFFFFFFu - (unsigned)(kk & 0xFFFFFFFFull));
    unsigned bits = (unsigned)(kk >> 32);
    int v = bits > 0x3F000000u ? 1 : 0;          // prob > 0.5f strictly
    topi[b*NN + tid] = idx;
    valid[b*NN + tid] = v;
    if (v) atomicAdd(&s_vcnt, 1);
    int iy = idx >> 7;          // w = 128
    int ix = idx & 127;
    float yo = off[((size_t)b*2 + 0) * NPIX + idx];
    float xo = off[((size_t)b*2 + 1) * NPIX + idx];
    float xs = ((float)ix + 0.5f + xo) * 4.0f;   // STRIDE = 4
    float ys = ((float)iy + 0.5f + yo) * 4.0f;
    out_nodes[(b*NN + tid)*2 + 0] = xs;
    out_nodes[(b*NN + tid)*2 + 1] = ys;
  }
  __syncthreads();
  if (tid < NN) {
    int V = s_vcnt;
    int v = valid[b*NN + tid];
    inv_deg[b*NN + tid] = (v && V >= 2) ? 1.0f / (float)(V - 1) : 0.0f;
  }
}

// ---------------- Kernel 2: gather node features, mask by valid ----------------
__global__ __launch_bounds__(256) void k_gather(
    const float* __restrict__ nmap, const int* __restrict__ topi,
    const int* __restrict__ valid, float* __restrict__ x)
{
  const int bn = blockIdx.x;          // b*256 + n
  const int b = bn >> 8;
  const int c = threadIdx.x;
  int pix = topi[bn];
  int v = valid[bn];
  float val = nmap[(((size_t)b*CC + c) << 14) + pix];
  x[(size_t)bn*CC + c] = v ? val : 0.0f;
}

// ---------------- Kernel 3: column sum S[c] = sum_n x[n][c] ----------------
__global__ __launch_bounds__(256) void k_colsum(
    const float* __restrict__ x, float* __restrict__ S)
{
  const int b = blockIdx.x, c = threadIdx.x;
  const float* xb = x + (size_t)b*NN*CC;
  float s = 0.f;
  for (int n = 0; n < NN; ++n) s += xb[n*CC + c];
  S[b*CC + c] = s;
}

// ---------------- Kernel 4: fused GNN layer ----------------
// out = relu(x @ Wself + ((S - x)*inv_deg) @ Wnbr + bias) * valid
__global__ __launch_bounds__(256) void k_gnn(
    const float* __restrict__ x, const float* __restrict__ S,
    const float* __restrict__ inv_deg, const int* __restrict__ valid,
    const float* __restrict__ Wself, const float* __restrict__ Wnbr,
    const float* __restrict__ bias, float* __restrict__ xout,
    float* __restrict__ out_emb)   // may be null
{
  __shared__ float sx[8][CC];
  __shared__ float sz[8][CC];
  const int b = blockIdx.x >> 5;
  const int n0 = (blockIdx.x & 31) * 8;
  const int tid = threadIdx.x;
  float Sc = S[b*CC + tid];
  #pragma unroll
  for (int r = 0; r < 8; ++r) {
    float a = x[((size_t)(b*NN + n0 + r))*CC + tid];
    sx[r][tid] = a;
    float inv = inv_deg[b*NN + n0 + r];
    sz[r][tid] = (Sc - a) * inv;
  }
  __syncthreads();
  float acc[8];
  #pragma unroll
  for (int r = 0; r < 8; ++r) acc[r] = 0.f;
  for (int c = 0; c < CC; ++c) {
    float w1 = Wself[c*CC + tid];
    float w2 = Wnbr[c*CC + tid];
    #pragma unroll
    for (int r = 0; r < 8; ++r)
      acc[r] += sx[r][c]*w1 + sz[r][c]*w2;
  }
  float bv = bias[tid];
  #pragma unroll
  for (int r = 0; r < 8; ++r) {
    int v = valid[b*NN + n0 + r];
    float o = fmaxf(acc[r] + bv, 0.f);
    o = v ? o : 0.f;
    size_t oi = ((size_t)(b*NN + n0 + r))*CC + tid;
    xout[oi] = o;
    if (out_emb) out_emb[oi] = o;
  }
}

// ---------------- Kernel 5: u = x@Ws1[:C], v_t = (x@Ws1[C:])^T ----------------
__global__ __launch_bounds__(128) void k_uv(
    const float* __restrict__ x, const float* __restrict__ Ws1,
    float* __restrict__ u, float* __restrict__ vt)
{
  __shared__ float sx[8][CC];
  const int b = blockIdx.x >> 5;
  const int n0 = (blockIdx.x & 31) * 8;
  const int tid = threadIdx.x;     // h
  #pragma unroll
  for (int r = 0; r < 8; ++r)
    for (int c = tid; c < CC; c += 128)
      sx[r][c] = x[((size_t)(b*NN + n0 + r))*CC + c];
  __syncthreads();
  float au[8] = {0,0,0,0,0,0,0,0};
  float av[8] = {0,0,0,0,0,0,0,0};
  for (int c = 0; c < CC; ++c) {
    float w1 = Ws1[c*HH + tid];
    float w2 = Ws1[(CC + c)*HH + tid];
    #pragma unroll
    for (int r = 0; r < 8; ++r) { au[r] += sx[r][c]*w1; av[r] += sx[r][c]*w2; }
  }
  #pragma unroll
  for (int r = 0; r < 8; ++r) {
    u [((size_t)(b*NN + n0 + r))*HH + tid] = au[r];
    vt[((size_t)b*HH + tid)*NN + (n0 + r)] = av[r];
  }
}

// ---------------- Kernel 6: per-edge scorer ----------------
__global__ __launch_bounds__(256) void k_edges(
    const float* __restrict__ u, const float* __restrict__ vt,
    const float* __restrict__ bs1, const float* __restrict__ Ws2,
    const float* __restrict__ bs2, const int* __restrict__ valid,
    float* __restrict__ out_logits, float* __restrict__ out_keep)
{
  __shared__ float su[HH], sb1[HH], sw2[HH];
  const int b = blockIdx.x >> 8;
  const int i = blockIdx.x & 255;   // src node
  const int j = threadIdx.x;        // dst node
  if (j < HH) {
    su[j]  = u[((size_t)(b*NN + i))*HH + j];
    sb1[j] = bs1[j];
    sw2[j] = Ws2[j];
  }
  __syncthreads();
  float acc = 0.f;
  const float* vrow = vt + (size_t)b*HH*NN;
  for (int h = 0; h < HH; ++h) {
    float t = su[h] + vrow[h*NN + j] + sb1[h];
    acc += fmaxf(t, 0.f) * sw2[h];
  }
  acc += bs2[0];
  if (j != i) {
    int e = i*255 + (j < i ? j : j - 1);
    int ev = valid[b*NN + i] & valid[b*NN + j];
    out_logits[(size_t)b*EE + e] = acc;
    out_keep  [(size_t)b*EE + e] = (acc > 0.f && ev) ? 1.0f : 0.0f;
  }
}

extern "C" void kernel_launch(void* const* d_in, const int* in_sizes, int n_in,
                              void* d_out, int out_size, void* d_ws, size_t ws_size,
                              hipStream_t stream) {
  const float* jl    = (const float*)d_in[0];
  const float* off   = (const float*)d_in[1];
  const float* nmap  = (const float*)d_in[2];
  const float* Wself = (const float*)d_in[3];
  const float* Wnbr  = (const float*)d_in[4];
  const float* bg    = (const float*)d_in[5];
  const float* Ws1   = (const float*)d_in[6];
  const float* bs1   = (const float*)d_in[7];
  const float* Ws2   = (const float*)d_in[8];
  const float* bs2   = (const float*)d_in[9];

  char* ws = (char*)d_ws;
  int*   topi    = (int*)  (ws + 0);                 //  4 KiB
  int*   valid   = (int*)  (ws + 4096);              //  4 KiB
  float* inv_deg = (float*)(ws + 8192);              //  4 KiB
  float* S       = (float*)(ws + 12288);             //  4 KiB
  float* xa      = (float*)(ws + 16384);             //  1 MiB
  float* xb      = (float*)(ws + 16384 + 1048576);   //  1 MiB
  float* u       = (float*)(ws + 2113536);           //  512 KiB
  float* vt      = (float*)(ws + 2637824);           //  512 KiB

  float* out        = (float*)d_out;
  float* out_nodes  = out;                  // [4,256,2]   -> 2048
  float* out_emb    = out + 2048;           // [4,256,256] -> 262144
  float* out_logits = out + 264192;         // [4,65280]   -> 261120
  float* out_keep   = out + 525312;         // [4,65280]   -> 261120

  hipLaunchKernelGGL(k_topk,   dim3(BB),     dim3(1024), 0, stream,
                     jl, off, topi, valid, inv_deg, out_nodes);
  hipLaunchKernelGGL(k_gather, dim3(BB*NN),  dim3(256),  0, stream,
                     nmap, topi, valid, xa);

  float* xc = xa; float* xn = xb;
  for (int l = 0; l < 3; ++l) {
    hipLaunchKernelGGL(k_colsum, dim3(BB),   dim3(256), 0, stream, xc, S);
    hipLaunchKernelGGL(k_gnn,    dim3(BB*32),dim3(256), 0, stream,
                       xc, S, inv_deg, valid,
                       Wself + (size_t)l*CC*CC, Wnbr + (size_t)l*CC*CC, bg + l*CC,
                       xn, (l == 2) ? out_emb : (float*)nullptr);
    float* t = xc; xc = xn; xn = t;
  }

  hipLaunchKernelGGL(k_uv,    dim3(BB*32), dim3(128), 0, stream, xc, Ws1, u, vt);
  hipLaunchKernelGGL(k_edges, dim3(BB*NN), dim3(256), 0, stream,
                     u, vt, bs1, Ws2, bs2, valid, out_logits, out_keep);
}

// Round 3
// 151.438 us; speedup vs baseline: 3.2280x; 1.8279x over previous
//
#include <hip/hip_runtime.h>

#define NPIX 16384   // 128*128
#define NN   256     // max_nodes
#define CC   256     // NFEAT
#define HH   128     // SCORER_HIDDEN
#define EE   65280   // NN*(NN-1)
#define BB   4
#define NG   8       // histogram privatization groups
#define RR   2       // rows per thread in GEMM kernels

// ---------------- Kernel 1: sigmoid + exact top-k via radix select ----------------
// key = (float_bits(prob) << 32) | (0xFFFFFFFF - idx)  -- unique per pixel
// top-256 keys descending => prob desc, ties -> lower idx first (matches jax.lax.top_k)
__global__ __launch_bounds__(1024) void k_topk(
    const float* __restrict__ jl, const float* __restrict__ off,
    int* __restrict__ topi, int* __restrict__ valid, float* __restrict__ inv_deg,
    float* __restrict__ out_nodes)
{
  __shared__ unsigned long long keys[NPIX];     // 128 KiB
  __shared__ unsigned long long s_sel[NN];      // 2 KiB
  __shared__ int hist[NG][256];                 // 8 KiB
  __shared__ int histT[256];                    // 1 KiB
  __shared__ unsigned long long s_T;
  __shared__ int s_digit, s_krem, s_cnt, s_vcnt, s_break;

  const int b = blockIdx.x;
  const int tid = threadIdx.x;
  const int grp = (tid >> 7) & (NG - 1);
  if (tid == 0) { s_cnt = 0; s_vcnt = 0; s_break = 0; }

  const float* p = jl + (size_t)b * NPIX;
  for (int i = tid; i < NPIX; i += 1024) {
    float x = p[i];
    float pr = 1.0f / (1.0f + expf(-x));
    unsigned bits = __float_as_uint(pr);        // prob in (0,1]: bits monotone
    keys[i] = ((unsigned long long)bits << 32) | (unsigned)(0xFFFFFFFFu - (unsigned)i);
  }

  // ---- radix select: find T = 256th largest key ----
  unsigned long long prefix = 0;
  int k = NN;
  int shift = 56;
  for (int pass = 0; pass < 8; ++pass) {
    shift = 56 - 8 * pass;
    for (int i = tid; i < NG * 256; i += 1024) ((int*)hist)[i] = 0;
    __syncthreads();   // also covers keys[] writes on pass 0 / s_digit reads on later passes
    unsigned long long pmask = (pass == 0) ? 0ULL : (~0ULL << (shift + 8));
    for (int i = tid; i < NPIX; i += 1024) {
      unsigned long long kk = keys[i];
      if ((kk & pmask) == prefix)
        atomicAdd(&hist[grp][(int)((kk >> shift) & 255)], 1);
    }
    __syncthreads();
    if (tid < 256) {
      int t = 0;
      #pragma unroll
      for (int g = 0; g < NG; ++g) t += hist[g][tid];
      histT[tid] = t;
    }
    __syncthreads();
    if (tid == 0) {
      int cum = 0, bb = 255;
      for (;; --bb) { cum += histT[bb]; if (cum >= k || bb == 0) break; }
      s_digit = bb;
      s_krem = k - (cum - histT[bb]);
      s_break = (histT[bb] == 1);
    }
    __syncthreads();
    prefix |= ((unsigned long long)s_digit) << shift;
    k = s_krem;
    if (s_break) break;
  }

  // ---- recover exact threshold key T (unique match of known-prefix bits) ----
  unsigned long long known_mask = (shift == 0) ? ~0ULL : (~0ULL << shift);
  for (int i = tid; i < NPIX; i += 1024) {
    unsigned long long kk = keys[i];
    if ((kk & known_mask) == prefix) s_T = kk;
  }
  __syncthreads();
  unsigned long long T = s_T;

  // ---- compact the exactly-256 keys >= T ----
  for (int i = tid; i < NPIX; i += 1024) {
    unsigned long long kk = keys[i];
    if (kk >= T) { int pos = atomicAdd(&s_cnt, 1); s_sel[pos] = kk; }
  }
  __syncthreads();

  // ---- bitonic sort 256 keys descending ----
  for (int kk2 = 2; kk2 <= NN; kk2 <<= 1) {
    for (int j = kk2 >> 1; j > 0; j >>= 1) {
      if (tid < NN) {
        int i = tid, l = i ^ j;
        if (l > i) {
          unsigned long long a = s_sel[i], c = s_sel[l];
          bool desc = (i & kk2) == 0;
          if (desc ? (a < c) : (a > c)) { s_sel[i] = c; s_sel[l] = a; }
        }
      }
      __syncthreads();
    }
  }

  // ---- emit topi / valid / nodes ----
  if (tid < NN) {
    unsigned long long kk = s_sel[tid];
    int idx = (int)(0xFFFFFFFFu - (unsigned)(kk & 0xFFFFFFFFull));
    unsigned bits = (unsigned)(kk >> 32);
    int v = bits > 0x3F000000u ? 1 : 0;          // prob > 0.5f strictly
    topi[b*NN + tid] = idx;
    valid[b*NN + tid] = v;
    if (v) atomicAdd(&s_vcnt, 1);
    int iy = idx >> 7;          // w = 128
    int ix = idx & 127;
    float yo = off[((size_t)b*2 + 0) * NPIX + idx];
    float xo = off[((size_t)b*2 + 1) * NPIX + idx];
    float xs = ((float)ix + 0.5f + xo) * 4.0f;   // STRIDE = 4
    float ys = ((float)iy + 0.5f + yo) * 4.0f;
    out_nodes[(b*NN + tid)*2 + 0] = xs;
    out_nodes[(b*NN + tid)*2 + 1] = ys;
  }
  __syncthreads();
  if (tid < NN) {
    int V = s_vcnt;
    int v = valid[b*NN + tid];
    inv_deg[b*NN + tid] = (v && V >= 2) ? 1.0f / (float)(V - 1) : 0.0f;
  }
}

// ---------------- Kernel 2: gather node features + fused colsum into S0 ----------------
__global__ __launch_bounds__(256) void k_gather(
    const float* __restrict__ nmap, const int* __restrict__ topi,
    const int* __restrict__ valid, float* __restrict__ x, float* __restrict__ S0)
{
  const int bn = blockIdx.x;          // b*256 + n
  const int b = bn >> 8;
  const int c = threadIdx.x;
  int pix = topi[bn];
  int v = valid[bn];
  float val = v ? nmap[(((size_t)b*CC + c) << 14) + pix] : 0.0f;
  x[(size_t)bn*CC + c] = val;
  if (val != 0.0f) atomicAdd(&S0[b*CC + c], val);
}

// ---------------- Kernel 3: fused GNN layer (+ colsum of output into Snext) ----------------
// out = relu(x @ Wself + ((S - x)*inv_deg) @ Wnbr + bias) * valid
__global__ __launch_bounds__(256) void k_gnn(
    const float* __restrict__ x, const float* __restrict__ S,
    const float* __restrict__ inv_deg, const int* __restrict__ valid,
    const float* __restrict__ Wself, const float* __restrict__ Wnbr,
    const float* __restrict__ bias, float* __restrict__ xout,
    float* __restrict__ Snext,     // may be null
    float* __restrict__ out_emb)   // may be null
{
  __shared__ float sx[RR][CC];
  __shared__ float sz[RR][CC];
  const int b = blockIdx.x >> 7;            // 128 row-groups per image
  const int n0 = (blockIdx.x & 127) * RR;
  const int tid = threadIdx.x;              // output column
  float Sc = S[b*CC + tid];
  #pragma unroll
  for (int r = 0; r < RR; ++r) {
    float a = x[((size_t)(b*NN + n0 + r))*CC + tid];
    sx[r][tid] = a;
    sz[r][tid] = (Sc - a) * inv_deg[b*NN + n0 + r];
  }
  __syncthreads();
  float acc0 = 0.f, acc1 = 0.f;
  #pragma unroll 8
  for (int c = 0; c < CC; ++c) {
    float w1 = Wself[c*CC + tid];
    float w2 = Wnbr[c*CC + tid];
    acc0 += sx[0][c]*w1 + sz[0][c]*w2;
    acc1 += sx[1][c]*w1 + sz[1][c]*w2;
  }
  float bv = bias[tid];
  int v0 = valid[b*NN + n0];
  int v1 = valid[b*NN + n0 + 1];
  float o0 = fmaxf(acc0 + bv, 0.f); o0 = v0 ? o0 : 0.f;
  float o1 = fmaxf(acc1 + bv, 0.f); o1 = v1 ? o1 : 0.f;
  size_t i0 = ((size_t)(b*NN + n0))*CC + tid;
  size_t i1 = i0 + CC;
  xout[i0] = o0;
  xout[i1] = o1;
  if (out_emb) { out_emb[i0] = o0; out_emb[i1] = o1; }
  if (Snext) {
    float cs = o0 + o1;
    if (cs != 0.f) atomicAdd(&Snext[b*CC + tid], cs);
  }
}

// ---------------- Kernel 4: u = x@Ws1[:C], v_t = (x@Ws1[C:])^T ----------------
__global__ __launch_bounds__(128) void k_uv(
    const float* __restrict__ x, const float* __restrict__ Ws1,
    float* __restrict__ u, float* __restrict__ vt)
{
  __shared__ float sx[RR][CC];
  const int b = blockIdx.x >> 7;            // 128 row-groups per image
  const int n0 = (blockIdx.x & 127) * RR;
  const int tid = threadIdx.x;              // h
  #pragma unroll
  for (int r = 0; r < RR; ++r)
    for (int c = tid; c < CC; c += 128)
      sx[r][c] = x[((size_t)(b*NN + n0 + r))*CC + c];
  __syncthreads();
  float au0 = 0.f, au1 = 0.f, av0 = 0.f, av1 = 0.f;
  #pragma unroll 8
  for (int c = 0; c < CC; ++c) {
    float w1 = Ws1[c*HH + tid];
    float w2 = Ws1[(CC + c)*HH + tid];
    au0 += sx[0][c]*w1; av0 += sx[0][c]*w2;
    au1 += sx[1][c]*w1; av1 += sx[1][c]*w2;
  }
  u [((size_t)(b*NN + n0 + 0))*HH + tid] = au0;
  u [((size_t)(b*NN + n0 + 1))*HH + tid] = au1;
  vt[((size_t)b*HH + tid)*NN + (n0 + 0)] = av0;
  vt[((size_t)b*HH + tid)*NN + (n0 + 1)] = av1;
}

// ---------------- Kernel 5: per-edge scorer ----------------
__global__ __launch_bounds__(256) void k_edges(
    const float* __restrict__ u, const float* __restrict__ vt,
    const float* __restrict__ bs1, const float* __restrict__ Ws2,
    const float* __restrict__ bs2, const int* __restrict__ valid,
    float* __restrict__ out_logits, float* __restrict__ out_keep)
{
  __shared__ float su[HH], sb1[HH], sw2[HH];
  const int b = blockIdx.x >> 8;
  const int i = blockIdx.x & 255;   // src node
  const int j = threadIdx.x;        // dst node
  if (j < HH) {
    su[j]  = u[((size_t)(b*NN + i))*HH + j];
    sb1[j] = bs1[j];
    sw2[j] = Ws2[j];
  }
  __syncthreads();
  float acc = 0.f;
  const float* vrow = vt + (size_t)b*HH*NN;
  #pragma unroll 8
  for (int h = 0; h < HH; ++h) {
    float t = su[h] + vrow[h*NN + j] + sb1[h];
    acc += fmaxf(t, 0.f) * sw2[h];
  }
  acc += bs2[0];
  if (j != i) {
    int e = i*255 + (j < i ? j : j - 1);
    int ev = valid[b*NN + i] & valid[b*NN + j];
    out_logits[(size_t)b*EE + e] = acc;
    out_keep  [(size_t)b*EE + e] = (acc > 0.f && ev) ? 1.0f : 0.0f;
  }
}

extern "C" void kernel_launch(void* const* d_in, const int* in_sizes, int n_in,
                              void* d_out, int out_size, void* d_ws, size_t ws_size,
                              hipStream_t stream) {
  const float* jl    = (const float*)d_in[0];
  const float* off   = (const float*)d_in[1];
  const float* nmap  = (const float*)d_in[2];
  const float* Wself = (const float*)d_in[3];
  const float* Wnbr  = (const float*)d_in[4];
  const float* bg    = (const float*)d_in[5];
  const float* Ws1   = (const float*)d_in[6];
  const float* bs1   = (const float*)d_in[7];
  const float* Ws2   = (const float*)d_in[8];
  const float* bs2   = (const float*)d_in[9];

  char* ws = (char*)d_ws;
  int*   topi    = (int*)  (ws + 0);                 //  4 KiB
  int*   valid   = (int*)  (ws + 4096);              //  4 KiB
  float* inv_deg = (float*)(ws + 8192);              //  4 KiB
  float* Sbuf    = (float*)(ws + 12288);             // 16 KiB (4 layers' colsums)
  float* xa      = (float*)(ws + 28672);             //  1 MiB
  float* xb      = (float*)(ws + 28672 + 1048576);   //  1 MiB
  float* u       = (float*)(ws + 2125824);           //  512 KiB
  float* vt      = (float*)(ws + 2650112);           //  512 KiB

  float* out        = (float*)d_out;
  float* out_nodes  = out;                  // [4,256,2]   -> 2048
  float* out_emb    = out + 2048;           // [4,256,256] -> 262144
  float* out_logits = out + 264192;         // [4,65280]   -> 261120
  float* out_keep   = out + 525312;         // [4,65280]   -> 261120

  hipMemsetAsync(Sbuf, 0, 4 * BB * CC * sizeof(float), stream);

  hipLaunchKernelGGL(k_topk,   dim3(BB),     dim3(1024), 0, stream,
                     jl, off, topi, valid, inv_deg, out_nodes);
  hipLaunchKernelGGL(k_gather, dim3(BB*NN),  dim3(256),  0, stream,
                     nmap, topi, valid, xa, Sbuf);

  float* xc = xa; float* xn = xb;
  for (int l = 0; l < 3; ++l) {
    hipLaunchKernelGGL(k_gnn, dim3(BB*(NN/RR)), dim3(256), 0, stream,
                       xc, Sbuf + l*BB*CC, inv_deg, valid,
                       Wself + (size_t)l*CC*CC, Wnbr + (size_t)l*CC*CC, bg + l*CC,
                       xn,
                       (l < 2) ? (Sbuf + (l+1)*BB*CC) : (float*)nullptr,
                       (l == 2) ? out_emb : (float*)nullptr);
    float* t = xc; xc = xn; xn = t;
  }

  hipLaunchKernelGGL(k_uv,    dim3(BB*(NN/RR)), dim3(128), 0, stream, xc, Ws1, u, vt);
  hipLaunchKernelGGL(k_edges, dim3(BB*NN),      dim3(256), 0, stream,
                     u, vt, bs1, Ws2, bs2, valid, out_logits, out_keep);
}

// Round 4
// 117.039 us; speedup vs baseline: 4.1768x; 1.2939x over previous
//
#include <hip/hip_runtime.h>

#define NPIX 16384   // 128*128
#define NN   256     // max_nodes
#define CC   256     // NFEAT
#define HH   128     // SCORER_HIDDEN
#define EE   65280   // NN*(NN-1)
#define BB   4
#define NG   8       // histogram privatization groups
#define RR   2       // rows per thread in GEMM kernels

// ---------------- Kernel 1: sigmoid + exact top-k via register radix select ----------------
// key = (float_bits(prob) << 32) | (0xFFFFFFFF - idx)  -- unique per pixel
// top-256 keys descending => prob desc, ties -> lower idx first (matches jax.lax.top_k)
__global__ __launch_bounds__(1024) void k_topk(
    const float* __restrict__ jl, const float* __restrict__ off,
    int* __restrict__ topi, int* __restrict__ valid, float* __restrict__ inv_deg,
    float* __restrict__ out_nodes)
{
  __shared__ int hist[NG][257];                 // padded: group copies on distinct banks
  __shared__ int histT[256];
  __shared__ unsigned long long s_sel[NN];
  __shared__ unsigned long long s_T;
  __shared__ int s_digit, s_krem, s_cnt, s_vcnt, s_break;

  const int b = blockIdx.x;
  const int tid = threadIdx.x;
  const int grp = (tid >> 7) & (NG - 1);
  if (tid == 0) { s_cnt = 0; s_vcnt = 0; }

  // ---- keys in registers: 16 per thread, coalesced stride-1024 loads ----
  unsigned long long rk[16];
  const float* p = jl + (size_t)b * NPIX;
  #pragma unroll
  for (int r = 0; r < 16; ++r) {
    int i = tid + (r << 10);
    float x = p[i];
    float pr = 1.0f / (1.0f + expf(-x));
    unsigned bits = __float_as_uint(pr);        // prob in (0,1]: bits monotone
    rk[r] = ((unsigned long long)bits << 32) | (unsigned)(0xFFFFFFFFu - (unsigned)i);
  }

  // ---- radix select: find T = 256th largest key ----
  unsigned long long prefix = 0;
  int k = NN;
  int shift = 56;
  int brk = 0;
  for (int pass = 0; pass < 8 && !brk; ++pass) {
    shift = 56 - 8 * pass;
    for (int i = tid; i < NG * 257; i += 1024) ((int*)hist)[i] = 0;
    __syncthreads();
    unsigned long long pmask = (pass == 0) ? 0ULL : (~0ULL << (shift + 8));
    #pragma unroll
    for (int r = 0; r < 16; ++r) {
      unsigned long long kk = rk[r];
      if ((kk & pmask) == prefix)
        atomicAdd(&hist[grp][(int)((kk >> shift) & 255)], 1);
    }
    __syncthreads();
    if (tid < 256) {
      int t = 0;
      #pragma unroll
      for (int g = 0; g < NG; ++g) t += hist[g][tid];
      histT[tid] = t;
    }
    __syncthreads();
    // wave 0: suffix scan over 256 bins (4 bins/lane) + boundary detect, no serial chain
    if (tid < 64) {
      int h0 = histT[4*tid + 0], h1 = histT[4*tid + 1];
      int h2 = histT[4*tid + 2], h3 = histT[4*tid + 3];
      int tot = h0 + h1 + h2 + h3;
      int suf = tot;
      #pragma unroll
      for (int d = 1; d < 64; d <<= 1) {
        int o = __shfl_down(suf, d);
        if (tid + d < 64) suf += o;
      }
      int above = suf - tot;          // sum over bins > 4*tid+3
      int c3 = h3 + above;
      int c2 = c3 + h2;
      int c1 = c2 + h1;
      int c0 = c1 + h0;
      if      (c3 >= k && above < k) { s_digit = 4*tid+3; s_krem = k - above; s_break = (h3 == 1); }
      else if (c2 >= k && c3    < k) { s_digit = 4*tid+2; s_krem = k - c3;    s_break = (h2 == 1); }
      else if (c1 >= k && c2    < k) { s_digit = 4*tid+1; s_krem = k - c2;    s_break = (h1 == 1); }
      else if (c0 >= k && c1    < k) { s_digit = 4*tid+0; s_krem = k - c1;    s_break = (h0 == 1); }
    }
    __syncthreads();
    prefix |= ((unsigned long long)s_digit) << shift;
    k = s_krem;
    brk = s_break;
  }

  // ---- recover exact threshold key T ----
  if (shift == 0) {
    if (tid == 0) s_T = prefix;
  } else {
    unsigned long long known_mask = ~0ULL << shift;
    #pragma unroll
    for (int r = 0; r < 16; ++r)
      if ((rk[r] & known_mask) == prefix) s_T = rk[r];
  }
  __syncthreads();
  unsigned long long T = s_T;

  // ---- compact the exactly-256 keys >= T (order irrelevant) ----
  #pragma unroll
  for (int r = 0; r < 16; ++r) {
    unsigned long long kk = rk[r];
    if (kk >= T) { int pos = atomicAdd(&s_cnt, 1); s_sel[pos] = kk; }
  }
  __syncthreads();

  // ---- order by rank-by-count (256 broadcast LDS reads, no barriers) ----
  int my_rank = -1, my_v = 0;
  if (tid < NN) {
    unsigned long long mine = s_sel[tid];
    int rank = 0;
    #pragma unroll 16
    for (int j = 0; j < NN; ++j) rank += (s_sel[j] > mine) ? 1 : 0;
    unsigned bits = (unsigned)(mine >> 32);
    int v = bits > 0x3F000000u ? 1 : 0;          // prob > 0.5f strictly
    int idx = (int)(0xFFFFFFFFu - (unsigned)(mine & 0xFFFFFFFFull));
    if (v) atomicAdd(&s_vcnt, 1);
    topi[b*NN + rank] = idx;
    valid[b*NN + rank] = v;
    int iy = idx >> 7;          // w = 128
    int ix = idx & 127;
    float yo = off[((size_t)b*2 + 0) * NPIX + idx];
    float xo = off[((size_t)b*2 + 1) * NPIX + idx];
    out_nodes[(b*NN + rank)*2 + 0] = ((float)ix + 0.5f + xo) * 4.0f;   // STRIDE = 4
    out_nodes[(b*NN + rank)*2 + 1] = ((float)iy + 0.5f + yo) * 4.0f;
    my_rank = rank; my_v = v;
  }
  __syncthreads();
  if (tid < NN) {
    int V = s_vcnt;
    inv_deg[b*NN + my_rank] = (my_v && V >= 2) ? 1.0f / (float)(V - 1) : 0.0f;
  }
}

// ---------------- Kernel 2: gather node features + fused colsum into S0 ----------------
__global__ __launch_bounds__(256) void k_gather(
    const float* __restrict__ nmap, const int* __restrict__ topi,
    const int* __restrict__ valid, float* __restrict__ x, float* __restrict__ S0)
{
  const int bn = blockIdx.x;          // b*256 + n
  const int b = bn >> 8;
  const int c = threadIdx.x;
  int pix = topi[bn];
  int v = valid[bn];
  float val = v ? nmap[(((size_t)b*CC + c) << 14) + pix] : 0.0f;
  x[(size_t)bn*CC + c] = val;
  if (val != 0.0f) atomicAdd(&S0[b*CC + c], val);
}

// ---------------- Kernel 3: fused GNN layer (+ colsum of output into Snext) ----------------
// out = relu(x @ Wself + ((S - x)*inv_deg) @ Wnbr + bias) * valid
__global__ __launch_bounds__(256) void k_gnn(
    const float* __restrict__ x, const float* __restrict__ S,
    const float* __restrict__ inv_deg, const int* __restrict__ valid,
    const float* __restrict__ Wself, const float* __restrict__ Wnbr,
    const float* __restrict__ bias, float* __restrict__ xout,
    float* __restrict__ Snext,     // may be null
    float* __restrict__ out_emb)   // may be null
{
  __shared__ float sx[RR][CC];
  __shared__ float sz[RR][CC];
  const int b = blockIdx.x >> 7;            // 128 row-groups per image
  const int n0 = (blockIdx.x & 127) * RR;
  const int tid = threadIdx.x;              // output column
  float Sc = S[b*CC + tid];
  #pragma unroll
  for (int r = 0; r < RR; ++r) {
    float a = x[((size_t)(b*NN + n0 + r))*CC + tid];
    sx[r][tid] = a;
    sz[r][tid] = (Sc - a) * inv_deg[b*NN + n0 + r];
  }
  __syncthreads();
  float acc0 = 0.f, acc1 = 0.f;
  #pragma unroll 8
  for (int c = 0; c < CC; ++c) {
    float w1 = Wself[c*CC + tid];
    float w2 = Wnbr[c*CC + tid];
    acc0 += sx[0][c]*w1 + sz[0][c]*w2;
    acc1 += sx[1][c]*w1 + sz[1][c]*w2;
  }
  float bv = bias[tid];
  int v0 = valid[b*NN + n0];
  int v1 = valid[b*NN + n0 + 1];
  float o0 = fmaxf(acc0 + bv, 0.f); o0 = v0 ? o0 : 0.f;
  float o1 = fmaxf(acc1 + bv, 0.f); o1 = v1 ? o1 : 0.f;
  size_t i0 = ((size_t)(b*NN + n0))*CC + tid;
  size_t i1 = i0 + CC;
  xout[i0] = o0;
  xout[i1] = o1;
  if (out_emb) { out_emb[i0] = o0; out_emb[i1] = o1; }
  if (Snext) {
    float cs = o0 + o1;
    if (cs != 0.f) atomicAdd(&Snext[b*CC + tid], cs);
  }
}

// ---------------- Kernel 4: u = x@Ws1[:C], v_t = (x@Ws1[C:])^T ----------------
__global__ __launch_bounds__(128) void k_uv(
    const float* __restrict__ x, const float* __restrict__ Ws1,
    float* __restrict__ u, float* __restrict__ vt)
{
  __shared__ float sx[RR][CC];
  const int b = blockIdx.x >> 7;            // 128 row-groups per image
  const int n0 = (blockIdx.x & 127) * RR;
  const int tid = threadIdx.x;              // h
  #pragma unroll
  for (int r = 0; r < RR; ++r)
    for (int c = tid; c < CC; c += 128)
      sx[r][c] = x[((size_t)(b*NN + n0 + r))*CC + c];
  __syncthreads();
  float au0 = 0.f, au1 = 0.f, av0 = 0.f, av1 = 0.f;
  #pragma unroll 8
  for (int c = 0; c < CC; ++c) {
    float w1 = Ws1[c*HH + tid];
    float w2 = Ws1[(CC + c)*HH + tid];
    au0 += sx[0][c]*w1; av0 += sx[0][c]*w2;
    au1 += sx[1][c]*w1; av1 += sx[1][c]*w2;
  }
  u [((size_t)(b*NN + n0 + 0))*HH + tid] = au0;
  u [((size_t)(b*NN + n0 + 1))*HH + tid] = au1;
  vt[((size_t)b*HH + tid)*NN + (n0 + 0)] = av0;
  vt[((size_t)b*HH + tid)*NN + (n0 + 1)] = av1;
}

// ---------------- Kernel 5: per-edge scorer ----------------
__global__ __launch_bounds__(256) void k_edges(
    const float* __restrict__ u, const float* __restrict__ vt,
    const float* __restrict__ bs1, const float* __restrict__ Ws2,
    const float* __restrict__ bs2, const int* __restrict__ valid,
    float* __restrict__ out_logits, float* __restrict__ out_keep)
{
  __shared__ float su[HH], sb1[HH], sw2[HH];
  const int b = blockIdx.x >> 8;
  const int i = blockIdx.x & 255;   // src node
  const int j = threadIdx.x;        // dst node
  if (j < HH) {
    su[j]  = u[((size_t)(b*NN + i))*HH + j];
    sb1[j] = bs1[j];
    sw2[j] = Ws2[j];
  }
  __syncthreads();
  float acc = 0.f;
  const float* vrow = vt + (size_t)b*HH*NN;
  #pragma unroll 8
  for (int h = 0; h < HH; ++h) {
    float t = su[h] + vrow[h*NN + j] + sb1[h];
    acc += fmaxf(t, 0.f) * sw2[h];
  }
  acc += bs2[0];
  if (j != i) {
    int e = i*255 + (j < i ? j : j - 1);
    int ev = valid[b*NN + i] & valid[b*NN + j];
    out_logits[(size_t)b*EE + e] = acc;
    out_keep  [(size_t)b*EE + e] = (acc > 0.f && ev) ? 1.0f : 0.0f;
  }
}

extern "C" void kernel_launch(void* const* d_in, const int* in_sizes, int n_in,
                              void* d_out, int out_size, void* d_ws, size_t ws_size,
                              hipStream_t stream) {
  const float* jl    = (const float*)d_in[0];
  const float* off   = (const float*)d_in[1];
  const float* nmap  = (const float*)d_in[2];
  const float* Wself = (const float*)d_in[3];
  const float* Wnbr  = (const float*)d_in[4];
  const float* bg    = (const float*)d_in[5];
  const float* Ws1   = (const float*)d_in[6];
  const float* bs1   = (const float*)d_in[7];
  const float* Ws2   = (const float*)d_in[8];
  const float* bs2   = (const float*)d_in[9];

  char* ws = (char*)d_ws;
  int*   topi    = (int*)  (ws + 0);                 //  4 KiB
  int*   valid   = (int*)  (ws + 4096);              //  4 KiB
  float* inv_deg = (float*)(ws + 8192);              //  4 KiB
  float* Sbuf    = (float*)(ws + 12288);             // 16 KiB (4 layers' colsums)
  float* xa      = (float*)(ws + 28672);             //  1 MiB
  float* xb      = (float*)(ws + 28672 + 1048576);   //  1 MiB
  float* u       = (float*)(ws + 2125824);           //  512 KiB
  float* vt      = (float*)(ws + 2650112);           //  512 KiB

  float* out        = (float*)d_out;
  float* out_nodes  = out;                  // [4,256,2]   -> 2048
  float* out_emb    = out + 2048;           // [4,256,256] -> 262144
  float* out_logits = out + 264192;         // [4,65280]   -> 261120
  float* out_keep   = out + 525312;         // [4,65280]   -> 261120

  hipMemsetAsync(Sbuf, 0, 4 * BB * CC * sizeof(float), stream);

  hipLaunchKernelGGL(k_topk,   dim3(BB),     dim3(1024), 0, stream,
                     jl, off, topi, valid, inv_deg, out_nodes);
  hipLaunchKernelGGL(k_gather, dim3(BB*NN),  dim3(256),  0, stream,
                     nmap, topi, valid, xa, Sbuf);

  float* xc = xa; float* xn = xb;
  for (int l = 0; l < 3; ++l) {
    hipLaunchKernelGGL(k_gnn, dim3(BB*(NN/RR)), dim3(256), 0, stream,
                       xc, Sbuf + l*BB*CC, inv_deg, valid,
                       Wself + (size_t)l*CC*CC, Wnbr + (size_t)l*CC*CC, bg + l*CC,
                       xn,
                       (l < 2) ? (Sbuf + (l+1)*BB*CC) : (float*)nullptr,
                       (l == 2) ? out_emb : (float*)nullptr);
    float* t = xc; xc = xn; xn = t;
  }

  hipLaunchKernelGGL(k_uv,    dim3(BB*(NN/RR)), dim3(128), 0, stream, xc, Ws1, u, vt);
  hipLaunchKernelGGL(k_edges, dim3(BB*NN),      dim3(256), 0, stream,
                     u, vt, bs1, Ws2, bs2, valid, out_logits, out_keep);
}